// Round 1
// 331.889 us; speedup vs baseline: 1.0611x; 1.0611x over previous
//
#include <hip/hip_runtime.h>

#define B_ 512
#define L_ 512
#define N_ 128
#define TM 256          // boundary: fwd produces alpha_255, bwd produces beta_255
#define C_BIAS 3.0f

typedef _Float16 h2_t __attribute__((ext_vector_type(2)));

__device__ __forceinline__ float dot2f(h2_t a, h2_t b, float c) {
#if __has_builtin(__builtin_amdgcn_fdot2)
    return __builtin_amdgcn_fdot2(a, b, c, false);
#else
    return c + (float)a[0] * (float)b[0] + (float)a[1] * (float)b[1];
#endif
}

// ---- full-rate VALU wave-64 reductions via DPP (no ds_swizzle chains) ----
// sequence: quad_perm[1,0,3,2], quad_perm[2,3,0,1], row_half_mirror,
// row_mirror, row_bcast15, row_bcast31 ; lane 63 holds the full result.
#define DPP_STEP_MAX(v, ctrl)                                                   \
    {                                                                           \
        int _t = __builtin_amdgcn_update_dpp(__float_as_int(v),                 \
                    __float_as_int(v), ctrl, 0xf, 0xf, false);                  \
        v = fmaxf(v, __int_as_float(_t));                                       \
    }
#define DPP_STEP_ADD(v, ctrl)                                                   \
    {                                                                           \
        int _t = __builtin_amdgcn_update_dpp(__float_as_int(v),                 \
                    __float_as_int(v), ctrl, 0xf, 0xf, false);                  \
        v = v + __int_as_float(_t);                                             \
    }

__device__ __forceinline__ float wave_max(float v) {
    DPP_STEP_MAX(v, 0xB1);   // quad_perm [1,0,3,2]
    DPP_STEP_MAX(v, 0x4E);   // quad_perm [2,3,0,1]
    DPP_STEP_MAX(v, 0x141);  // row_half_mirror
    DPP_STEP_MAX(v, 0x140);  // row_mirror
    DPP_STEP_MAX(v, 0x142);  // row_bcast15
    DPP_STEP_MAX(v, 0x143);  // row_bcast31
    return __int_as_float(__builtin_amdgcn_readlane(__float_as_int(v), 63));
}
__device__ __forceinline__ float wave_sum(float v) {
    DPP_STEP_ADD(v, 0xB1);
    DPP_STEP_ADD(v, 0x4E);
    DPP_STEP_ADD(v, 0x141);
    DPP_STEP_ADD(v, 0x140);
    DPP_STEP_ADD(v, 0x142);  // lane63 path stays exact; other lanes don't matter
    DPP_STEP_ADD(v, 0x143);
    return __int_as_float(__builtin_amdgcn_readlane(__float_as_int(v), 63));
}

// ---------------------------------------------------------------------------
// norm_kernel: 1024 blocks x 64 threads (1 wave each) = 1 wave per SIMD.
// blockIdx: b = blockIdx.x >> 1 ; bw = blockIdx.x & 1 (0 = forward, 1 = backward).
// Forward  : alpha_t[j] = m_t*(LSE_i(alpha_{t-1}[i]+T[i][j]) + em_t[j]) + (1-m_t)*alpha_{t-1}[j]
//            lane owns states j=2l,2l+1 (ET COLUMN fragments in regs).
// Backward : beta_t[i]  = m_{t+1}*(LSE_j(T[i][j]+em_{t+1}[j]+beta_{t+1}[j])) + (1-m_{t+1})*beta_{t+1}[i]
//            lane owns states i=2l,2l+1 (ET ROW fragments in regs); the LDS
//            broadcast vector is F[j]=exp(beta[j]+em[j]-M-C).
// Z_b = LSE_j(alpha_255[j] + beta_255[j])   (combined afterwards).
// Wave-synchronous: zero barriers, zero vmcnt(0) drains. Lagged DPP max.
// ---------------------------------------------------------------------------
__global__ __launch_bounds__(64) void norm_kernel(
    const float* __restrict__ em, const int* __restrict__ tg,
    const float* __restrict__ mask, const float* __restrict__ st,
    const float* __restrict__ trans,
    float* __restrict__ alpha, float* __restrict__ beta,
    float* __restrict__ pathf, float* __restrict__ pathb)
{
    __shared__ __align__(16) h2_t Eh[64];   // broadcast vector (E fwd / F bwd), 128 f16
    __shared__ float Mlds[TM];              // mask row half

    const int l  = threadIdx.x;
    const int b  = blockIdx.x >> 1;
    const int bw = blockIdx.x & 1;
    const size_t base = (size_t)b * L_ * N_;
    const int bL = b * L_;

    if (bw == 0) {
        // ================= FORWARD =================
        // path-score half: t in [1, TM)
        float pacc = 0.f;
        for (int t = 1 + l; t < TM; t += 64) {
            int cur  = tg[bL + t];
            int prev = tg[bL + t - 1];
            pacc += mask[bL + t] * (trans[prev * N_ + cur] + em[base + (size_t)t * N_ + cur]);
        }
        pacc = wave_sum(pacc);
        if (l == 0) {
            int t0 = tg[bL];
            pathf[b] = pacc + st[t0] + em[base + t0];
        }

#pragma unroll
        for (int k = 0; k < 4; ++k) Mlds[l + 64 * k] = mask[bL + l + 64 * k];

        // ET column fragments: et0/et1[k] = (ET[2k][j], ET[2k+1][j]) for j=2l / 2l+1
        h2_t et0[64], et1[64];
#pragma unroll
        for (int k = 0; k < 64; ++k) {
            float2 r0 = *(const float2*)(trans + (2 * k    ) * N_ + 2 * l);
            float2 r1 = *(const float2*)(trans + (2 * k + 1) * N_ + 2 * l);
            h2_t a, c;
            a[0] = (_Float16)__expf(r0.x); a[1] = (_Float16)__expf(r1.x);
            c[0] = (_Float16)__expf(r0.y); c[1] = (_Float16)__expf(r1.y);
            et0[k] = a; et1[k] = c;
        }

        // init alpha_0
        float2 e0 = *(const float2*)(em + base + 2 * l);
        float2 s2 = *(const float2*)(st + 2 * l);
        float ns0 = s2.x + e0.x;
        float ns1 = s2.y + e0.y;
        float Mprev = wave_max(fmaxf(ns0, ns1));
        {
            h2_t eo;
            eo[0] = (_Float16)__expf(ns0 - Mprev - C_BIAS);
            eo[1] = (_Float16)__expf(ns1 - Mprev - C_BIAS);
            Eh[l] = eo;
        }

        float2 pipe0 = *(const float2*)(em + base + (size_t)1 * N_ + 2 * l);
        float2 pipe1 = *(const float2*)(em + base + (size_t)2 * N_ + 2 * l);
        float2 pipe2 = *(const float2*)(em + base + (size_t)3 * N_ + 2 * l);
        float2 pipe3 = *(const float2*)(em + base + (size_t)4 * N_ + 2 * l);

        auto step = [&](int t, float2& slot) {
            float2 emv = slot;
            int tpf = t + 4; if (tpf > TM - 1) tpf = TM - 1;
            slot = *(const float2*)(em + base + (size_t)tpf * N_ + 2 * l);
            float mk = Mlds[t];

            float mx = wave_max(fmaxf(ns0, ns1));   // max(ns_{t-1}); overlaps dots

            float a0 = 0.f, a1 = 0.f, a2 = 0.f, a3 = 0.f;
            float c0 = 0.f, c1 = 0.f, c2 = 0.f, c3 = 0.f;
            const float4* E4 = (const float4*)Eh;
#pragma unroll
            for (int r = 0; r < 16; ++r) {
                float4 blk = E4[r];
                const h2_t* e2 = (const h2_t*)&blk;
                a0 = dot2f(e2[0], et0[4 * r + 0], a0);
                a1 = dot2f(e2[1], et0[4 * r + 1], a1);
                a2 = dot2f(e2[2], et0[4 * r + 2], a2);
                a3 = dot2f(e2[3], et0[4 * r + 3], a3);
                c0 = dot2f(e2[0], et1[4 * r + 0], c0);
                c1 = dot2f(e2[1], et1[4 * r + 1], c1);
                c2 = dot2f(e2[2], et1[4 * r + 2], c2);
                c3 = dot2f(e2[3], et1[4 * r + 3], c3);
            }
            float s_0 = (a0 + a1) + (a2 + a3);
            float s_1 = (c0 + c1) + (c2 + c3);

            float badd = Mprev + C_BIAS;
            float nxt0 = __logf(s_0) + badd + emv.x;
            float nxt1 = __logf(s_1) + badd + emv.y;
            float im = 1.f - mk;
            ns0 = mk * nxt0 + im * ns0;
            ns1 = mk * nxt1 + im * ns1;

            Mprev = mx;
            h2_t eo;
            eo[0] = (_Float16)__expf(ns0 - mx - C_BIAS);
            eo[1] = (_Float16)__expf(ns1 - mx - C_BIAS);
            Eh[l] = eo;
        };

        for (int tt = 1; tt + 3 < TM; tt += 4) {
            step(tt    , pipe0);
            step(tt + 1, pipe1);
            step(tt + 2, pipe2);
            step(tt + 3, pipe3);
        }
        step(TM - 3, pipe0);
        step(TM - 2, pipe1);
        step(TM - 1, pipe2);

        *(float2*)(alpha + b * N_ + 2 * l) = make_float2(ns0, ns1);
    } else {
        // ================= BACKWARD =================
        // path-score half: t in [TM, L)
        float pacc = 0.f;
        for (int t = TM + l; t < L_; t += 64) {
            int cur  = tg[bL + t];
            int prev = tg[bL + t - 1];
            pacc += mask[bL + t] * (trans[prev * N_ + cur] + em[base + (size_t)t * N_ + cur]);
        }
        pacc = wave_sum(pacc);
        if (l == 0) pathb[b] = pacc;

#pragma unroll
        for (int k = 0; k < 4; ++k) Mlds[l + 64 * k] = mask[bL + TM + l + 64 * k];

        // ET row fragments: er0/er1[k] = (ET[i][2k], ET[i][2k+1]) for i=2l / 2l+1
        h2_t er0[64], er1[64];
#pragma unroll
        for (int k4 = 0; k4 < 32; ++k4) {
            float4 q0 = *(const float4*)(trans + (2 * l    ) * N_ + 4 * k4);
            float4 q1 = *(const float4*)(trans + (2 * l + 1) * N_ + 4 * k4);
            h2_t a, c;
            a[0] = (_Float16)__expf(q0.x); a[1] = (_Float16)__expf(q0.y);
            er0[2 * k4] = a;
            a[0] = (_Float16)__expf(q0.z); a[1] = (_Float16)__expf(q0.w);
            er0[2 * k4 + 1] = a;
            c[0] = (_Float16)__expf(q1.x); c[1] = (_Float16)__expf(q1.y);
            er1[2 * k4] = c;
            c[0] = (_Float16)__expf(q1.z); c[1] = (_Float16)__expf(q1.w);
            er1[2 * k4 + 1] = c;
        }

        // init at u=511: beta_511 = 0 ; v = beta + em_511
        float2 e0 = *(const float2*)(em + base + (size_t)(L_ - 1) * N_ + 2 * l);
        float b0 = 0.f, b1 = 0.f;
        float v0 = e0.x, v1 = e0.y;
        float Mprev = wave_max(fmaxf(v0, v1));
        {
            h2_t eo;
            eo[0] = (_Float16)__expf(v0 - Mprev - C_BIAS);
            eo[1] = (_Float16)__expf(v1 - Mprev - C_BIAS);
            Eh[l] = eo;
        }

        float2 pipe0 = *(const float2*)(em + base + (size_t)510 * N_ + 2 * l);
        float2 pipe1 = *(const float2*)(em + base + (size_t)509 * N_ + 2 * l);
        float2 pipe2 = *(const float2*)(em + base + (size_t)508 * N_ + 2 * l);
        float2 pipe3 = *(const float2*)(em + base + (size_t)507 * N_ + 2 * l);

        // iter t (510 down to 255): consumes F_{t+1} (in Eh), em_t (pipe), mask_{t+1}
        auto step = [&](int t, float2& slot) {
            float2 emt = slot;
            int tpf = t - 4; if (tpf < TM - 1) tpf = TM - 1;
            slot = *(const float2*)(em + base + (size_t)tpf * N_ + 2 * l);
            float mk = Mlds[t + 1 - TM];

            float mx = wave_max(fmaxf(v0, v1));   // max(v_{t+1}); overlaps dots

            float a0 = 0.f, a1 = 0.f, a2 = 0.f, a3 = 0.f;
            float c0 = 0.f, c1 = 0.f, c2 = 0.f, c3 = 0.f;
            const float4* F4 = (const float4*)Eh;
#pragma unroll
            for (int r = 0; r < 16; ++r) {
                float4 blk = F4[r];
                const h2_t* f2 = (const h2_t*)&blk;
                a0 = dot2f(f2[0], er0[4 * r + 0], a0);
                a1 = dot2f(f2[1], er0[4 * r + 1], a1);
                a2 = dot2f(f2[2], er0[4 * r + 2], a2);
                a3 = dot2f(f2[3], er0[4 * r + 3], a3);
                c0 = dot2f(f2[0], er1[4 * r + 0], c0);
                c1 = dot2f(f2[1], er1[4 * r + 1], c1);
                c2 = dot2f(f2[2], er1[4 * r + 2], c2);
                c3 = dot2f(f2[3], er1[4 * r + 3], c3);
            }
            float s_0 = (a0 + a1) + (a2 + a3);
            float s_1 = (c0 + c1) + (c2 + c3);

            float badd = Mprev + C_BIAS;
            float upd0 = __logf(s_0) + badd;
            float upd1 = __logf(s_1) + badd;
            float im = 1.f - mk;
            b0 = mk * upd0 + im * b0;
            b1 = mk * upd1 + im * b1;

            v0 = b0 + emt.x;
            v1 = b1 + emt.y;
            Mprev = mx;
            h2_t eo;
            eo[0] = (_Float16)__expf(v0 - mx - C_BIAS);
            eo[1] = (_Float16)__expf(v1 - mx - C_BIAS);
            Eh[l] = eo;
        };

        for (int tt = 510; tt >= 258; tt -= 4) {   // 64 groups x 4 = t 510..255
            step(tt    , pipe0);
            step(tt - 1, pipe1);
            step(tt - 2, pipe2);
            step(tt - 3, pipe3);
        }

        *(float2*)(beta + b * N_ + 2 * l) = make_float2(b0, b1);
    }
}

// ---------------------------------------------------------------------------
// zres_kernel: 512 blocks x 1 wave. Block b: zres[b] = LSE_j(alpha[j]+beta[j])
//              - pathf[b] - pathb[b].  (parallelized replacement for the old
//              single-block combine loop — was ~155us of single-CU serialism)
// ---------------------------------------------------------------------------
__global__ __launch_bounds__(64) void zres_kernel(
    const float* __restrict__ alpha, const float* __restrict__ beta,
    const float* __restrict__ pathf, const float* __restrict__ pathb,
    float* __restrict__ zres)
{
    const int l = threadIdx.x;
    const int b = blockIdx.x;
    float2 av = *(const float2*)(alpha + b * N_ + 2 * l);
    float2 bv = *(const float2*)(beta  + b * N_ + 2 * l);
    float v0 = av.x + bv.x;
    float v1 = av.y + bv.y;
    float m = wave_max(fmaxf(v0, v1));
    float s = wave_sum(__expf(v0 - m) + __expf(v1 - m));
    if (l == 0) zres[b] = m + __logf(s) - pathf[b] - pathb[b];
}

// ---------------------------------------------------------------------------
// mean_kernel: 1 wave. out = mean(zres). 8 values/lane (2x float4) + DPP tree.
// ---------------------------------------------------------------------------
__global__ __launch_bounds__(64) void mean_kernel(
    const float* __restrict__ zres, float* __restrict__ out)
{
    const int l = threadIdx.x;
    const float4* z4 = (const float4*)zres;
    float4 a = z4[2 * l];
    float4 c = z4[2 * l + 1];
    float acc = ((a.x + a.y) + (a.z + a.w)) + ((c.x + c.y) + (c.z + c.w));
    acc = wave_sum(acc);
    if (l == 0) out[0] = acc * (1.0f / (float)B_);
}

// ---------------------------------------------------------------------------
extern "C" void kernel_launch(void* const* d_in, const int* in_sizes, int n_in,
                              void* d_out, int out_size, void* d_ws, size_t ws_size,
                              hipStream_t stream) {
    const float* emission    = (const float*)d_in[0];
    const int*   target      = (const int*)  d_in[1];
    const float* mask        = (const float*)d_in[2];
    const float* start_trans = (const float*)d_in[3];
    const float* trans       = (const float*)d_in[4];
    float* out = (float*)d_out;

    float* ws_f  = (float*)d_ws;
    float* alpha = ws_f;                        // 512*128
    float* beta  = ws_f + B_ * N_;              // 512*128
    float* pathf = ws_f + 2 * B_ * N_;          // 512
    float* pathb = ws_f + 2 * B_ * N_ + B_;     // 512
    float* zres  = ws_f + 2 * B_ * N_ + 2 * B_; // 512

    norm_kernel<<<2 * B_, 64, 0, stream>>>(emission, target, mask, start_trans,
                                           trans, alpha, beta, pathf, pathb);
    zres_kernel<<<B_, 64, 0, stream>>>(alpha, beta, pathf, pathb, zres);
    mean_kernel<<<1, 64, 0, stream>>>(zres, out);
}

// Round 2
// 329.349 us; speedup vs baseline: 1.0693x; 1.0077x over previous
//
#include <hip/hip_runtime.h>

#define B_ 512
#define L_ 512
#define N_ 128
#define TM 256          // boundary: fwd produces alpha_255, bwd produces beta_255
#define C_BIAS 3.0f

typedef _Float16 h2_t __attribute__((ext_vector_type(2)));

__device__ __forceinline__ float dot2f(h2_t a, h2_t b, float c) {
#if __has_builtin(__builtin_amdgcn_fdot2)
    return __builtin_amdgcn_fdot2(a, b, c, false);
#else
    return c + (float)a[0] * (float)b[0] + (float)a[1] * (float)b[1];
#endif
}

// ---- full-rate VALU wave-64 reductions via DPP (no ds_swizzle chains) ----
// sequence: quad_perm[1,0,3,2], quad_perm[2,3,0,1], row_half_mirror,
// row_mirror, row_bcast15, row_bcast31 ; lane 63 holds the full result.
#define DPP_STEP_MAX(v, ctrl)                                                   \
    {                                                                           \
        int _t = __builtin_amdgcn_update_dpp(__float_as_int(v),                 \
                    __float_as_int(v), ctrl, 0xf, 0xf, false);                  \
        v = fmaxf(v, __int_as_float(_t));                                       \
    }
#define DPP_STEP_ADD(v, ctrl)                                                   \
    {                                                                           \
        int _t = __builtin_amdgcn_update_dpp(__float_as_int(v),                 \
                    __float_as_int(v), ctrl, 0xf, 0xf, false);                  \
        v = v + __int_as_float(_t);                                             \
    }

// lane 63 holds the full-wave max; no broadcast (for single-lane LDS write)
__device__ __forceinline__ float wave_max63(float v) {
    DPP_STEP_MAX(v, 0xB1);   // quad_perm [1,0,3,2]
    DPP_STEP_MAX(v, 0x4E);   // quad_perm [2,3,0,1]
    DPP_STEP_MAX(v, 0x141);  // row_half_mirror
    DPP_STEP_MAX(v, 0x140);  // row_mirror
    DPP_STEP_MAX(v, 0x142);  // row_bcast15
    DPP_STEP_MAX(v, 0x143);  // row_bcast31
    return v;
}
__device__ __forceinline__ float wave_max(float v) {
    v = wave_max63(v);
    return __int_as_float(__builtin_amdgcn_readlane(__float_as_int(v), 63));
}
__device__ __forceinline__ float wave_sum(float v) {
    DPP_STEP_ADD(v, 0xB1);
    DPP_STEP_ADD(v, 0x4E);
    DPP_STEP_ADD(v, 0x141);
    DPP_STEP_ADD(v, 0x140);
    DPP_STEP_ADD(v, 0x142);  // lane63 path stays exact; other lanes don't matter
    DPP_STEP_ADD(v, 0x143);
    return __int_as_float(__builtin_amdgcn_readlane(__float_as_int(v), 63));
}

// Raw barrier: order LDS ops (lgkmcnt) but do NOT drain vmcnt — the em
// prefetch pipes are wave-private and must stay in flight across steps.
__device__ __forceinline__ void sync_lds() {
    asm volatile("s_waitcnt lgkmcnt(0)" ::: "memory");
    __builtin_amdgcn_s_barrier();
    asm volatile("" ::: "memory");
}

// ---------------------------------------------------------------------------
// norm_kernel: 1024 blocks x 128 threads (2 waves) = 2048 waves = 2 waves/SIMD.
// Each chain (b, dir) is split across the block's 2 waves: lane owns ONE state
// j = tid (fwd: ET column j in regs; bwd: ET row i = tid in regs).
// Per step: one raw s_barrier; E vector and cross-wave running max are
// double-buffered in LDS (Ebuf[2][128] f16, Hm[2][2]) so one sync suffices.
// Numerics identical to the 1-wave version: E_t = exp(ns_t - max(ns_{t-1}) - C).
// ---------------------------------------------------------------------------
__global__ __launch_bounds__(128, 2) void norm_kernel(
    const float* __restrict__ em, const int* __restrict__ tg,
    const float* __restrict__ mask, const float* __restrict__ st,
    const float* __restrict__ trans,
    float* __restrict__ alpha, float* __restrict__ beta,
    float* __restrict__ pathf, float* __restrict__ pathb)
{
    __shared__ __align__(16) _Float16 Ebuf[2][128];  // double-buffered E/F vector
    __shared__ float Mlds[TM];                       // mask row half
    __shared__ __align__(8) float Hm[2][2];          // per-wave local max, dbuf
    __shared__ float Psum[2];                        // path-score partials

    const int tid = threadIdx.x;
    const int w   = tid >> 6;
    const int b   = blockIdx.x >> 1;
    const int bw  = blockIdx.x & 1;
    const size_t base = (size_t)b * L_ * N_;
    const int bL = b * L_;

    if (bw == 0) {
        // ================= FORWARD =================
        // path-score half: t in [1, TM)
        float pacc = 0.f;
        for (int t = 1 + tid; t < TM; t += 128) {
            int cur  = tg[bL + t];
            int prev = tg[bL + t - 1];
            pacc += mask[bL + t] * (trans[prev * N_ + cur] + em[base + (size_t)t * N_ + cur]);
        }
        pacc = wave_sum(pacc);
        if ((tid & 63) == 0) Psum[w] = pacc;

#pragma unroll
        for (int k = 0; k < 2; ++k) Mlds[tid + 128 * k] = mask[bL + tid + 128 * k];

        // ET column fragments for state j = tid: et[k] = (eT[2k][j], eT[2k+1][j])
        h2_t et[64];
#pragma unroll
        for (int k = 0; k < 64; ++k) {
            float r0 = trans[(2 * k    ) * N_ + tid];
            float r1 = trans[(2 * k + 1) * N_ + tid];
            h2_t a;
            a[0] = (_Float16)__expf(r0); a[1] = (_Float16)__expf(r1);
            et[k] = a;
        }

        // init alpha_0
        float ns = st[tid] + em[base + tid];
        {
            float hl = wave_max63(ns);
            if ((tid & 63) == 63) Hm[0][w] = hl;
        }
        sync_lds();
        float gmax0 = fmaxf(Hm[0][0], Hm[0][1]);
        float Mprev = gmax0;
        Ebuf[0][tid] = (_Float16)__expf(ns - gmax0 - C_BIAS);
        if (tid == 0) {
            int t0 = tg[bL];
            pathf[b] = Psum[0] + Psum[1] + st[t0] + em[base + t0];
        }
        sync_lds();

        float pipe0 = em[base + (size_t)1 * N_ + tid];
        float pipe1 = em[base + (size_t)2 * N_ + tid];
        float pipe2 = em[base + (size_t)3 * N_ + tid];
        float pipe3 = em[base + (size_t)4 * N_ + tid];

        auto step = [&](int t, float& slot) {
            float emv = slot;
            int tpf = t + 4; if (tpf > TM - 1) tpf = TM - 1;
            slot = em[base + (size_t)tpf * N_ + tid];
            float mk = Mlds[t];
            const int cu = t & 1, pv = cu ^ 1;

            // max(ns_{t-1}): written by both waves at end of step t-1
            float2 hm = *(const float2*)&Hm[pv][0];
            float gmax = fmaxf(hm.x, hm.y);

            float a0 = 0.f, a1 = 0.f, a2 = 0.f, a3 = 0.f;
            const float4* E4 = (const float4*)(&Ebuf[pv][0]);
#pragma unroll
            for (int r = 0; r < 16; ++r) {
                float4 blk = E4[r];
                const h2_t* e2 = (const h2_t*)&blk;
                a0 = dot2f(e2[0], et[4 * r + 0], a0);
                a1 = dot2f(e2[1], et[4 * r + 1], a1);
                a2 = dot2f(e2[2], et[4 * r + 2], a2);
                a3 = dot2f(e2[3], et[4 * r + 3], a3);
            }
            float s_ = (a0 + a1) + (a2 + a3);

            float nxt = __logf(s_) + Mprev + C_BIAS + emv;
            float im = 1.f - mk;
            ns = mk * nxt + im * ns;

            float hl = wave_max63(ns);
            if ((tid & 63) == 63) Hm[cu][w] = hl;
            Ebuf[cu][tid] = (_Float16)__expf(ns - gmax - C_BIAS);
            Mprev = gmax;
            sync_lds();
        };

        for (int tt = 1; tt + 3 < TM; tt += 4) {
            step(tt    , pipe0);
            step(tt + 1, pipe1);
            step(tt + 2, pipe2);
            step(tt + 3, pipe3);
        }
        step(TM - 3, pipe0);
        step(TM - 2, pipe1);
        step(TM - 1, pipe2);

        alpha[b * N_ + tid] = ns;
    } else {
        // ================= BACKWARD =================
        // path-score half: t in [TM, L)
        float pacc = 0.f;
        for (int t = TM + tid; t < L_; t += 128) {
            int cur  = tg[bL + t];
            int prev = tg[bL + t - 1];
            pacc += mask[bL + t] * (trans[prev * N_ + cur] + em[base + (size_t)t * N_ + cur]);
        }
        pacc = wave_sum(pacc);
        if ((tid & 63) == 0) Psum[w] = pacc;

#pragma unroll
        for (int k = 0; k < 2; ++k) Mlds[tid + 128 * k] = mask[bL + TM + tid + 128 * k];

        // ET row fragments for state i = tid: er[k] = (eT[i][2k], eT[i][2k+1])
        h2_t er[64];
#pragma unroll
        for (int k4 = 0; k4 < 32; ++k4) {
            float4 q = *(const float4*)(trans + tid * N_ + 4 * k4);
            h2_t a;
            a[0] = (_Float16)__expf(q.x); a[1] = (_Float16)__expf(q.y);
            er[2 * k4] = a;
            a[0] = (_Float16)__expf(q.z); a[1] = (_Float16)__expf(q.w);
            er[2 * k4 + 1] = a;
        }

        // init at u=511: beta_511 = 0 ; v = beta + em_511
        float bv = 0.f;
        float v = em[base + (size_t)(L_ - 1) * N_ + tid];
        {
            float hl = wave_max63(v);
            if ((tid & 63) == 63) Hm[0][w] = hl;
        }
        sync_lds();
        float gmax0 = fmaxf(Hm[0][0], Hm[0][1]);
        float Mprev = gmax0;
        Ebuf[0][tid] = (_Float16)__expf(v - gmax0 - C_BIAS);
        if (tid == 0) pathb[b] = Psum[0] + Psum[1];
        sync_lds();

        float pipe0 = em[base + (size_t)510 * N_ + tid];
        float pipe1 = em[base + (size_t)509 * N_ + tid];
        float pipe2 = em[base + (size_t)508 * N_ + tid];
        float pipe3 = em[base + (size_t)507 * N_ + tid];

        // iter u (510 down to 255): consumes F_{u+1} (Ebuf), em_u, mask_{u+1}
        auto step = [&](int u, float& slot) {
            float emt = slot;
            int tpf = u - 4; if (tpf < TM - 1) tpf = TM - 1;
            slot = em[base + (size_t)tpf * N_ + tid];
            float mk = Mlds[u + 1 - TM];
            const int cu = (u & 1) ^ 1, pv = cu ^ 1;

            // max(v_{u+1})
            float2 hm = *(const float2*)&Hm[pv][0];
            float gmax = fmaxf(hm.x, hm.y);

            float a0 = 0.f, a1 = 0.f, a2 = 0.f, a3 = 0.f;
            const float4* F4 = (const float4*)(&Ebuf[pv][0]);
#pragma unroll
            for (int r = 0; r < 16; ++r) {
                float4 blk = F4[r];
                const h2_t* f2 = (const h2_t*)&blk;
                a0 = dot2f(f2[0], er[4 * r + 0], a0);
                a1 = dot2f(f2[1], er[4 * r + 1], a1);
                a2 = dot2f(f2[2], er[4 * r + 2], a2);
                a3 = dot2f(f2[3], er[4 * r + 3], a3);
            }
            float s_ = (a0 + a1) + (a2 + a3);

            float upd = __logf(s_) + Mprev + C_BIAS;
            float im = 1.f - mk;
            bv = mk * upd + im * bv;

            v = bv + emt;
            float hl = wave_max63(v);
            if ((tid & 63) == 63) Hm[cu][w] = hl;
            Ebuf[cu][tid] = (_Float16)__expf(v - gmax - C_BIAS);
            Mprev = gmax;
            sync_lds();
        };

        for (int uu = 510; uu >= 258; uu -= 4) {   // 64 groups x 4 = u 510..255
            step(uu    , pipe0);
            step(uu - 1, pipe1);
            step(uu - 2, pipe2);
            step(uu - 3, pipe3);
        }

        beta[b * N_ + tid] = bv;
    }
}

// ---------------------------------------------------------------------------
// zres_kernel: 512 blocks x 1 wave. Block b: zres[b] = LSE_j(alpha[j]+beta[j])
//              - pathf[b] - pathb[b].
// ---------------------------------------------------------------------------
__global__ __launch_bounds__(64) void zres_kernel(
    const float* __restrict__ alpha, const float* __restrict__ beta,
    const float* __restrict__ pathf, const float* __restrict__ pathb,
    float* __restrict__ zres)
{
    const int l = threadIdx.x;
    const int b = blockIdx.x;
    float2 av = *(const float2*)(alpha + b * N_ + 2 * l);
    float2 bv = *(const float2*)(beta  + b * N_ + 2 * l);
    float v0 = av.x + bv.x;
    float v1 = av.y + bv.y;
    float m = wave_max(fmaxf(v0, v1));
    float s = wave_sum(__expf(v0 - m) + __expf(v1 - m));
    if (l == 0) zres[b] = m + __logf(s) - pathf[b] - pathb[b];
}

// ---------------------------------------------------------------------------
// mean_kernel: 1 wave. out = mean(zres). 8 values/lane (2x float4) + DPP tree.
// ---------------------------------------------------------------------------
__global__ __launch_bounds__(64) void mean_kernel(
    const float* __restrict__ zres, float* __restrict__ out)
{
    const int l = threadIdx.x;
    const float4* z4 = (const float4*)zres;
    float4 a = z4[2 * l];
    float4 c = z4[2 * l + 1];
    float acc = ((a.x + a.y) + (a.z + a.w)) + ((c.x + c.y) + (c.z + c.w));
    acc = wave_sum(acc);
    if (l == 0) out[0] = acc * (1.0f / (float)B_);
}

// ---------------------------------------------------------------------------
extern "C" void kernel_launch(void* const* d_in, const int* in_sizes, int n_in,
                              void* d_out, int out_size, void* d_ws, size_t ws_size,
                              hipStream_t stream) {
    const float* emission    = (const float*)d_in[0];
    const int*   target      = (const int*)  d_in[1];
    const float* mask        = (const float*)d_in[2];
    const float* start_trans = (const float*)d_in[3];
    const float* trans       = (const float*)d_in[4];
    float* out = (float*)d_out;

    float* ws_f  = (float*)d_ws;
    float* alpha = ws_f;                        // 512*128
    float* beta  = ws_f + B_ * N_;              // 512*128
    float* pathf = ws_f + 2 * B_ * N_;          // 512
    float* pathb = ws_f + 2 * B_ * N_ + B_;     // 512
    float* zres  = ws_f + 2 * B_ * N_ + 2 * B_; // 512

    norm_kernel<<<2 * B_, 128, 0, stream>>>(emission, target, mask, start_trans,
                                            trans, alpha, beta, pathf, pathb);
    zres_kernel<<<B_, 64, 0, stream>>>(alpha, beta, pathf, pathb, zres);
    mean_kernel<<<1, 64, 0, stream>>>(zres, out);
}

// Round 3
// 302.684 us; speedup vs baseline: 1.1635x; 1.0881x over previous
//
#include <hip/hip_runtime.h>

#define B_ 512
#define L_ 512
#define N_ 128
#define TM 256          // boundary: fwd produces alpha_255, bwd produces beta_255
#define C_BIAS 3.0f

typedef _Float16 h2_t __attribute__((ext_vector_type(2)));
typedef _Float16 h8_t __attribute__((ext_vector_type(8)));
typedef float    f4_t __attribute__((ext_vector_type(4)));

// ---- full-rate VALU wave-64 reductions via DPP (no ds_swizzle chains) ----
#define DPP_STEP_MAX(v, ctrl)                                                   \
    {                                                                           \
        int _t = __builtin_amdgcn_update_dpp(__float_as_int(v),                 \
                    __float_as_int(v), ctrl, 0xf, 0xf, false);                  \
        v = fmaxf(v, __int_as_float(_t));                                       \
    }
#define DPP_STEP_ADD(v, ctrl)                                                   \
    {                                                                           \
        int _t = __builtin_amdgcn_update_dpp(__float_as_int(v),                 \
                    __float_as_int(v), ctrl, 0xf, 0xf, false);                  \
        v = v + __int_as_float(_t);                                             \
    }

__device__ __forceinline__ float wave_max(float v) {
    DPP_STEP_MAX(v, 0xB1);   // quad_perm [1,0,3,2]
    DPP_STEP_MAX(v, 0x4E);   // quad_perm [2,3,0,1]
    DPP_STEP_MAX(v, 0x141);  // row_half_mirror
    DPP_STEP_MAX(v, 0x140);  // row_mirror
    DPP_STEP_MAX(v, 0x142);  // row_bcast15
    DPP_STEP_MAX(v, 0x143);  // row_bcast31
    return __int_as_float(__builtin_amdgcn_readlane(__float_as_int(v), 63));
}
__device__ __forceinline__ float wave_sum(float v) {
    DPP_STEP_ADD(v, 0xB1);
    DPP_STEP_ADD(v, 0x4E);
    DPP_STEP_ADD(v, 0x141);
    DPP_STEP_ADD(v, 0x140);
    DPP_STEP_ADD(v, 0x142);  // lane63 path stays exact; other lanes don't matter
    DPP_STEP_ADD(v, 0x143);
    return __int_as_float(__builtin_amdgcn_readlane(__float_as_int(v), 63));
}

// ---------------------------------------------------------------------------
// norm_kernel: 1024 blocks x 64 threads (1 wave) = 1 wave/SIMD. Barrier-free,
// wave-synchronous (back to R1 structure). Per step, the 128-wide LSE matvec
// runs on the MATRIX pipe:
//   S[16*jt + (l&15)] = sum_i E[i] * eT[i][j]   via 8 j-tiles x 4 K-slices of
//   v_mfma_f32_16x16x32_f16, A = E broadcast-replicated over 16 rows (4x
//   ds_read_b128, row-uniform = LDS broadcast), B = static exp(trans) AGPR
//   fragments (zero per-step cost). D rows are replicated, so any reg works.
// Lanes 0-15 scatter S to LDS (16 banks, conflict-free); all lanes read their
// own (S[2l], S[2l+1]) and run the identical log/blend/exp update as before.
// Numerics: same f16 quantization + f32 accumulate + lagged-max + C_BIAS.
// ---------------------------------------------------------------------------
__global__ __launch_bounds__(64) void norm_kernel(
    const float* __restrict__ em, const int* __restrict__ tg,
    const float* __restrict__ mask, const float* __restrict__ st,
    const float* __restrict__ trans,
    float* __restrict__ alpha, float* __restrict__ beta,
    float* __restrict__ pathf, float* __restrict__ pathb)
{
    __shared__ __align__(16) _Float16 Eh[128];   // broadcast E/F vector (f16)
    __shared__ __align__(8)  float    Sl[128];   // matvec result scatter
    __shared__ float Mlds[TM];                   // mask row half

    const int l  = threadIdx.x;
    const int c  = l & 15;       // MFMA n-index (D col)
    const int h  = l >> 4;       // MFMA k-group
    const int b  = blockIdx.x >> 1;
    const int bw = blockIdx.x & 1;
    const size_t base = (size_t)b * L_ * N_;
    const int bL = b * L_;

    if (bw == 0) {
        // ================= FORWARD =================
        // path-score half: t in [1, TM)
        float pacc = 0.f;
        for (int t = 1 + l; t < TM; t += 64) {
            int cur  = tg[bL + t];
            int prev = tg[bL + t - 1];
            pacc += mask[bL + t] * (trans[prev * N_ + cur] + em[base + (size_t)t * N_ + cur]);
        }
        pacc = wave_sum(pacc);
        if (l == 0) {
            int t0 = tg[bL];
            pathf[b] = pacc + st[t0] + em[base + t0];
        }

#pragma unroll
        for (int k = 0; k < 4; ++k) Mlds[l + 64 * k] = mask[bL + l + 64 * k];

        // B-fragments: Bf[jt][ks][e] = exp(trans[32ks + 8h + e][16jt + c])
        // (column loads: 16 consecutive lanes read 16 consecutive floats)
        h8_t Bf[8][4];
#pragma unroll
        for (int jt = 0; jt < 8; ++jt)
#pragma unroll
            for (int ks = 0; ks < 4; ++ks) {
                h8_t f;
#pragma unroll
                for (int e = 0; e < 8; ++e)
                    f[e] = (_Float16)__expf(trans[(32 * ks + 8 * h + e) * N_ + 16 * jt + c]);
                Bf[jt][ks] = f;
            }

        // init alpha_0
        float2 e0 = *(const float2*)(em + base + 2 * l);
        float2 s2 = *(const float2*)(st + 2 * l);
        float ns0 = s2.x + e0.x;
        float ns1 = s2.y + e0.y;
        float Mprev = wave_max(fmaxf(ns0, ns1));
        {
            h2_t eo;
            eo[0] = (_Float16)__expf(ns0 - Mprev - C_BIAS);
            eo[1] = (_Float16)__expf(ns1 - Mprev - C_BIAS);
            ((h2_t*)Eh)[l] = eo;
        }

        float2 pipe0 = *(const float2*)(em + base + (size_t)1 * N_ + 2 * l);
        float2 pipe1 = *(const float2*)(em + base + (size_t)2 * N_ + 2 * l);
        float2 pipe2 = *(const float2*)(em + base + (size_t)3 * N_ + 2 * l);
        float2 pipe3 = *(const float2*)(em + base + (size_t)4 * N_ + 2 * l);

        auto step = [&](int t, float2& slot) {
            float2 emv = slot;
            int tpf = t + 4; if (tpf > TM - 1) tpf = TM - 1;
            slot = *(const float2*)(em + base + (size_t)tpf * N_ + 2 * l);
            float mk = Mlds[t];

            float mx = wave_max(fmaxf(ns0, ns1));   // max(ns_{t-1}); overlaps MFMA

            // A-fragments: E[32ks + 8h + e] — row-uniform broadcast reads
            const _Float16* Eb = (const _Float16*)Eh;
            h8_t A0 = *(const h8_t*)(Eb + 8 * h);
            h8_t A1 = *(const h8_t*)(Eb + 32 + 8 * h);
            h8_t A2 = *(const h8_t*)(Eb + 64 + 8 * h);
            h8_t A3 = *(const h8_t*)(Eb + 96 + 8 * h);

            f4_t z = {0.f, 0.f, 0.f, 0.f};
            f4_t acc[8];
#pragma unroll
            for (int jt = 0; jt < 8; ++jt) {
                f4_t a = __builtin_amdgcn_mfma_f32_16x16x32_f16(A0, Bf[jt][0], z, 0, 0, 0);
                a = __builtin_amdgcn_mfma_f32_16x16x32_f16(A1, Bf[jt][1], a, 0, 0, 0);
                a = __builtin_amdgcn_mfma_f32_16x16x32_f16(A2, Bf[jt][2], a, 0, 0, 0);
                a = __builtin_amdgcn_mfma_f32_16x16x32_f16(A3, Bf[jt][3], a, 0, 0, 0);
                acc[jt] = a;
            }
            if (l < 16) {
#pragma unroll
                for (int jt = 0; jt < 8; ++jt) Sl[16 * jt + c] = acc[jt][0];
            }
            float2 sv = *(const float2*)(Sl + 2 * l);

            float badd = Mprev + C_BIAS;
            float nxt0 = __logf(sv.x) + badd + emv.x;
            float nxt1 = __logf(sv.y) + badd + emv.y;
            float im = 1.f - mk;
            ns0 = mk * nxt0 + im * ns0;
            ns1 = mk * nxt1 + im * ns1;

            Mprev = mx;
            h2_t eo;
            eo[0] = (_Float16)__expf(ns0 - mx - C_BIAS);
            eo[1] = (_Float16)__expf(ns1 - mx - C_BIAS);
            ((h2_t*)Eh)[l] = eo;
        };

        for (int tt = 1; tt + 3 < TM; tt += 4) {
            step(tt    , pipe0);
            step(tt + 1, pipe1);
            step(tt + 2, pipe2);
            step(tt + 3, pipe3);
        }
        step(TM - 3, pipe0);
        step(TM - 2, pipe1);
        step(TM - 1, pipe2);

        *(float2*)(alpha + b * N_ + 2 * l) = make_float2(ns0, ns1);
    } else {
        // ================= BACKWARD =================
        // path-score half: t in [TM, L)
        float pacc = 0.f;
        for (int t = TM + l; t < L_; t += 64) {
            int cur  = tg[bL + t];
            int prev = tg[bL + t - 1];
            pacc += mask[bL + t] * (trans[prev * N_ + cur] + em[base + (size_t)t * N_ + cur]);
        }
        pacc = wave_sum(pacc);
        if (l == 0) pathb[b] = pacc;

#pragma unroll
        for (int k = 0; k < 4; ++k) Mlds[l + 64 * k] = mask[bL + TM + l + 64 * k];

        // B-fragments: Bf[it][ks][e] = exp(trans[16it + c][32ks + 8h + e])
        // (row loads: 8 consecutive floats per fragment → 2x float4)
        h8_t Bf[8][4];
#pragma unroll
        for (int it = 0; it < 8; ++it)
#pragma unroll
            for (int ks = 0; ks < 4; ++ks) {
                const float* p = trans + (size_t)(16 * it + c) * N_ + 32 * ks + 8 * h;
                float4 q0 = *(const float4*)p;
                float4 q1 = *(const float4*)(p + 4);
                h8_t f;
                f[0] = (_Float16)__expf(q0.x); f[1] = (_Float16)__expf(q0.y);
                f[2] = (_Float16)__expf(q0.z); f[3] = (_Float16)__expf(q0.w);
                f[4] = (_Float16)__expf(q1.x); f[5] = (_Float16)__expf(q1.y);
                f[6] = (_Float16)__expf(q1.z); f[7] = (_Float16)__expf(q1.w);
                Bf[it][ks] = f;
            }

        // init at u=511: beta_511 = 0 ; v = beta + em_511
        float2 e0 = *(const float2*)(em + base + (size_t)(L_ - 1) * N_ + 2 * l);
        float b0 = 0.f, b1 = 0.f;
        float v0 = e0.x, v1 = e0.y;
        float Mprev = wave_max(fmaxf(v0, v1));
        {
            h2_t eo;
            eo[0] = (_Float16)__expf(v0 - Mprev - C_BIAS);
            eo[1] = (_Float16)__expf(v1 - Mprev - C_BIAS);
            ((h2_t*)Eh)[l] = eo;
        }

        float2 pipe0 = *(const float2*)(em + base + (size_t)510 * N_ + 2 * l);
        float2 pipe1 = *(const float2*)(em + base + (size_t)509 * N_ + 2 * l);
        float2 pipe2 = *(const float2*)(em + base + (size_t)508 * N_ + 2 * l);
        float2 pipe3 = *(const float2*)(em + base + (size_t)507 * N_ + 2 * l);

        // iter t (510 down to 255): consumes F_{t+1} (Eh), em_t (pipe), mask_{t+1}
        auto step = [&](int t, float2& slot) {
            float2 emt = slot;
            int tpf = t - 4; if (tpf < TM - 1) tpf = TM - 1;
            slot = *(const float2*)(em + base + (size_t)tpf * N_ + 2 * l);
            float mk = Mlds[t + 1 - TM];

            float mx = wave_max(fmaxf(v0, v1));   // max(v_{t+1}); overlaps MFMA

            const _Float16* Fb = (const _Float16*)Eh;
            h8_t A0 = *(const h8_t*)(Fb + 8 * h);
            h8_t A1 = *(const h8_t*)(Fb + 32 + 8 * h);
            h8_t A2 = *(const h8_t*)(Fb + 64 + 8 * h);
            h8_t A3 = *(const h8_t*)(Fb + 96 + 8 * h);

            f4_t z = {0.f, 0.f, 0.f, 0.f};
            f4_t acc[8];
#pragma unroll
            for (int it = 0; it < 8; ++it) {
                f4_t a = __builtin_amdgcn_mfma_f32_16x16x32_f16(A0, Bf[it][0], z, 0, 0, 0);
                a = __builtin_amdgcn_mfma_f32_16x16x32_f16(A1, Bf[it][1], a, 0, 0, 0);
                a = __builtin_amdgcn_mfma_f32_16x16x32_f16(A2, Bf[it][2], a, 0, 0, 0);
                a = __builtin_amdgcn_mfma_f32_16x16x32_f16(A3, Bf[it][3], a, 0, 0, 0);
                acc[it] = a;
            }
            if (l < 16) {
#pragma unroll
                for (int it = 0; it < 8; ++it) Sl[16 * it + c] = acc[it][0];
            }
            float2 sv = *(const float2*)(Sl + 2 * l);

            float badd = Mprev + C_BIAS;
            float upd0 = __logf(sv.x) + badd;
            float upd1 = __logf(sv.y) + badd;
            float im = 1.f - mk;
            b0 = mk * upd0 + im * b0;
            b1 = mk * upd1 + im * b1;

            v0 = b0 + emt.x;
            v1 = b1 + emt.y;
            Mprev = mx;
            h2_t eo;
            eo[0] = (_Float16)__expf(v0 - mx - C_BIAS);
            eo[1] = (_Float16)__expf(v1 - mx - C_BIAS);
            ((h2_t*)Eh)[l] = eo;
        };

        for (int tt = 510; tt >= 258; tt -= 4) {   // 64 groups x 4 = t 510..255
            step(tt    , pipe0);
            step(tt - 1, pipe1);
            step(tt - 2, pipe2);
            step(tt - 3, pipe3);
        }

        *(float2*)(beta + b * N_ + 2 * l) = make_float2(b0, b1);
    }
}

// ---------------------------------------------------------------------------
// zres_kernel: 512 blocks x 1 wave. Block b: zres[b] = LSE_j(alpha[j]+beta[j])
//              - pathf[b] - pathb[b].
// ---------------------------------------------------------------------------
__global__ __launch_bounds__(64) void zres_kernel(
    const float* __restrict__ alpha, const float* __restrict__ beta,
    const float* __restrict__ pathf, const float* __restrict__ pathb,
    float* __restrict__ zres)
{
    const int l = threadIdx.x;
    const int b = blockIdx.x;
    float2 av = *(const float2*)(alpha + b * N_ + 2 * l);
    float2 bv = *(const float2*)(beta  + b * N_ + 2 * l);
    float v0 = av.x + bv.x;
    float v1 = av.y + bv.y;
    float m = wave_max(fmaxf(v0, v1));
    float s = wave_sum(__expf(v0 - m) + __expf(v1 - m));
    if (l == 0) zres[b] = m + __logf(s) - pathf[b] - pathb[b];
}

// ---------------------------------------------------------------------------
// mean_kernel: 1 wave. out = mean(zres). 8 values/lane (2x float4) + DPP tree.
// ---------------------------------------------------------------------------
__global__ __launch_bounds__(64) void mean_kernel(
    const float* __restrict__ zres, float* __restrict__ out)
{
    const int l = threadIdx.x;
    const float4* z4 = (const float4*)zres;
    float4 a = z4[2 * l];
    float4 c = z4[2 * l + 1];
    float acc = ((a.x + a.y) + (a.z + a.w)) + ((c.x + c.y) + (c.z + c.w));
    acc = wave_sum(acc);
    if (l == 0) out[0] = acc * (1.0f / (float)B_);
}

// ---------------------------------------------------------------------------
extern "C" void kernel_launch(void* const* d_in, const int* in_sizes, int n_in,
                              void* d_out, int out_size, void* d_ws, size_t ws_size,
                              hipStream_t stream) {
    const float* emission    = (const float*)d_in[0];
    const int*   target      = (const int*)  d_in[1];
    const float* mask        = (const float*)d_in[2];
    const float* start_trans = (const float*)d_in[3];
    const float* trans       = (const float*)d_in[4];
    float* out = (float*)d_out;

    float* ws_f  = (float*)d_ws;
    float* alpha = ws_f;                        // 512*128
    float* beta  = ws_f + B_ * N_;              // 512*128
    float* pathf = ws_f + 2 * B_ * N_;          // 512
    float* pathb = ws_f + 2 * B_ * N_ + B_;     // 512
    float* zres  = ws_f + 2 * B_ * N_ + 2 * B_; // 512

    norm_kernel<<<2 * B_, 64, 0, stream>>>(emission, target, mask, start_trans,
                                           trans, alpha, beta, pathf, pathb);
    zres_kernel<<<B_, 64, 0, stream>>>(alpha, beta, pathf, pathb, zres);
    mean_kernel<<<1, 64, 0, stream>>>(zres, out);
}